// Round 23
// baseline (158.702 us; speedup 1.0000x reference)
//
#include <hip/hip_runtime.h>
#include <hip/hip_bf16.h>
#include <stdint.h>

typedef unsigned short u16;
typedef __attribute__((ext_vector_type(8))) short short8;
typedef __attribute__((ext_vector_type(4))) float f32x4;
typedef __attribute__((ext_vector_type(4))) u16 u16x4;

#define S_LEN 2048
#define D_DIM 1024
#define NBATCH 4
#define BM 128
#define BN 128
#define BK 32

enum { MODE_QKV = 0, MODE_SC = 2, MODE_PV = 3 };

__device__ inline u16 f2bf(float f) {
  uint32_t u = __float_as_uint(f);
  uint32_t r = (u + 0x7fffu + ((u >> 16) & 1u)) >> 16;
  return (u16)r;
}

// one kernel casts x and the 3 weight matrices into the contiguous bf16 region
// out = [xb (NBATCH*S*D) | Wq (D*D) | Wk | Wv]
__global__ __launch_bounds__(256) void cast_all(
    const float* __restrict__ x, const float* __restrict__ wq,
    const float* __restrict__ wk, const float* __restrict__ wv,
    u16* __restrict__ out) {
  const int X4 = (NBATCH * S_LEN * D_DIM) / 4;
  const int W4 = (D_DIM * D_DIM) / 4;
  const int total = X4 + 3 * W4;
  int g = blockIdx.x * blockDim.x + threadIdx.x;
  int stride = gridDim.x * blockDim.x;
  for (; g < total; g += stride) {
    const float* src;
    int si;
    if (g < X4) { src = x; si = g; }
    else if (g < X4 + W4) { src = wq; si = g - X4; }
    else if (g < X4 + 2 * W4) { src = wk; si = g - X4 - W4; }
    else { src = wv; si = g - X4 - 2 * W4; }
    f32x4 v = *reinterpret_cast<const f32x4*>(src + (long)si * 4);
    u16x4 o;
    o[0] = f2bf(v[0]); o[1] = f2bf(v[1]); o[2] = f2bf(v[2]); o[3] = f2bf(v[3]);
    *reinterpret_cast<u16x4*>(out + (long)g * 4) = o;
  }
}

// C = A (bf16 [M,K]) * B^T (bf16 [N,K]) ; lda = ldb = K.
// MODE_QKV: BK=32, 3 blk/CU, XCD-local row panels — proven optimum.
// MODE_SC/PV: BK=64 staged as TWO [128][32] sub-tiles (row stride 64 B keeps
//   the proven free 2-way conflict level — R21's flat [128][64] was a 32-way
//   conflict and masked the test). One vmcnt(0)+barrier per 32 MFMAs (halved
//   drain count); 64 KB LDS still fits the grid-limited 2 blk/CU.
template <int MODE>
__global__ __launch_bounds__(256, 2) void gemm_bt(
    const u16* __restrict__ A, const u16* __restrict__ B, void* __restrict__ C,
    int K, long strideAb, long strideBb, long strideCb, int ldc,
    float* __restrict__ aux, int nb) {
  constexpr int NH = (MODE == MODE_QKV) ? 1 : 2;  // K=32 sub-tiles per stage
  __shared__ u16 As[2][BM * BK * NH];
  __shared__ u16 Bs[2][BN * BK * NH];
  __shared__ float ilds[BM];

  int br, bc, bz;
  if (MODE == MODE_SC) {
    int t;
    if (nb == NBATCH) {
      int lin = blockIdx.x;          // 0..543
      int xcd = lin & 7;
      bz = xcd >> 1;                 // batch on XCD pair {2b,2b+1}
      t = (xcd & 1) * 68 + (lin >> 3);
    } else {
      bz = blockIdx.z;
      t = blockIdx.x;
    }
    int r = (int)((sqrtf(8.0f * (float)t + 1.0f) - 1.0f) * 0.5f);
    while ((r + 1) * (r + 2) / 2 <= t) ++r;
    while (r * (r + 1) / 2 > t) --r;
    br = r;
    bc = t - r * (r + 1) / 2;
  } else if (MODE == MODE_PV) {
    int xr, bcl, ch;
    if (nb == NBATCH) {
      int lin = blockIdx.x;          // 0..511
      int xcd = lin & 7;
      bz = xcd >> 1;
      ch = xcd & 1;                  // column half (Vt 2MB L2-resident)
      int rank = lin >> 3;           // 0..63
      xr = rank >> 2;                // 0..15
      bcl = rank & 3;
      // CU-pair-balanced: ranks c and c+32 co-reside; br(xr)+br(xr+8)=15.
      br = (xr < 8) ? (15 - 2 * xr) : (2 * (xr - 8));
      bc = ch * 4 + bcl;
    } else {
      bz = blockIdx.z;
      xr = blockIdx.x;
      int nt = S_LEN / BM;
      br = (xr & 1) ? (xr >> 1) : (nt - 1 - (xr >> 1));
      bc = blockIdx.y;
    }
  } else {
    // MODE_QKV: XCD-locality mapping (confirmed lin&7 -> XCD round-robin).
    int lin = blockIdx.y * gridDim.x + blockIdx.x;  // 0..1535
    int xcd = lin & 7;
    int rank = lin >> 3;        // 0..191
    br = xcd * 8 + (rank & 7);  // rows [1024*xcd, 1024*(xcd+1))
    bc = rank >> 3;             // 0..23
    bz = 0;
  }

  const u16* Ab = A + (long)bz * strideAb;
  const u16* Bb = B + (long)bz * strideBb;

  const int rowBase = br * BM;
  const int colBase = bc * BN;
  int nkt = (MODE == MODE_PV) ? (br + 1) * (BM / (BK * NH)) : (K / (BK * NH));

  const int tid = threadIdx.x;
  const int lane = tid & 63;
  const int wave = tid >> 6;
  const int wr = wave >> 1, wc = wave & 1;
  const int l15 = lane & 15;
  const int g = lane >> 4;

  if (MODE == MODE_PV) {
    // inline row_inv: 2 threads/row, parity-strided scalar sum (correct for any nslot)
    int row = tid >> 1, half = tid & 1;
    const float* lp = aux + (long)bz * S_LEN * 32 + (long)(rowBase + row) * 32;
    int nslot = 2 * (br + 1);  // slots SC wrote for this row-block
    float s = 0.f;
    for (int k = half; k < nslot; k += 2) s += lp[k];
    s += __shfl_xor(s, 1);
    if (half == 0) ilds[row] = 1.f / s;
  }

  f32x4 acc[4][4];
#pragma unroll
  for (int i = 0; i < 4; i++)
#pragma unroll
    for (int j = 0; j < 4; j++) acc[i][j] = f32x4{0.f, 0.f, 0.f, 0.f};

  const int srow = tid >> 2;       // 0..63
  const int skc = (tid & 3) * 8;   // 0,8,16,24

  auto stage = [&](int buf, int kt) {
#pragma unroll
    for (int h = 0; h < NH; ++h) {
      const u16* ga = Ab + (long)(rowBase + srow) * K + kt * (BK * NH) + h * BK + skc;
      const u16* gb = Bb + (long)(colBase + srow) * K + kt * (BK * NH) + h * BK + skc;
      __builtin_amdgcn_global_load_lds(
          (const __attribute__((address_space(1))) void*)ga,
          (__attribute__((address_space(3))) void*)(&As[buf][h * 4096 + tid * 8]), 16, 0, 0);
      __builtin_amdgcn_global_load_lds(
          (const __attribute__((address_space(1))) void*)(ga + (long)64 * K),
          (__attribute__((address_space(3))) void*)(&As[buf][h * 4096 + 64 * BK + tid * 8]),
          16, 0, 0);
      __builtin_amdgcn_global_load_lds(
          (const __attribute__((address_space(1))) void*)gb,
          (__attribute__((address_space(3))) void*)(&Bs[buf][h * 4096 + tid * 8]), 16, 0, 0);
      __builtin_amdgcn_global_load_lds(
          (const __attribute__((address_space(1))) void*)(gb + (long)64 * K),
          (__attribute__((address_space(3))) void*)(&Bs[buf][h * 4096 + 64 * BK + tid * 8]),
          16, 0, 0);
    }
  };

  stage(0, 0);
  __syncthreads();  // drain tile-0 loads; also covers PV's ilds write
  int cur = 0;
  for (int kt = 0; kt < nkt; ++kt) {
    if (kt + 1 < nkt) stage(cur ^ 1, kt + 1);  // prefetch in flight during compute
#pragma unroll
    for (int h = 0; h < NH; ++h) {
      short8 af[4], bf[4];
#pragma unroll
      for (int i = 0; i < 4; i++)
        af[i] = *reinterpret_cast<const short8*>(
            &As[cur][h * 4096 + (wr * 64 + i * 16 + l15) * BK + g * 8]);
#pragma unroll
      for (int j = 0; j < 4; j++)
        bf[j] = *reinterpret_cast<const short8*>(
            &Bs[cur][h * 4096 + (wc * 64 + j * 16 + l15) * BK + g * 8]);
#pragma unroll
      for (int i = 0; i < 4; i++)
#pragma unroll
        for (int j = 0; j < 4; j++)
          acc[i][j] = __builtin_amdgcn_mfma_f32_16x16x32_bf16(af[i], bf[j], acc[i][j], 0, 0, 0);
    }
    __syncthreads();  // vmcnt(0)+lgkmcnt(0)+barrier: next tile ready, buf reusable
    cur ^= 1;
  }

  const int lr = g * 4;
  const int lc = l15;

  if (MODE == MODE_QKV) {
    u16* Cb = (u16*)C;  // Qb base; Kb at +seg; Vt at +2*seg
    const long seg = (long)NBATCH * S_LEN * D_DIM;
    const int segi = colBase >> 10;
    const int hb = colBase & 1023;
    if (segi < 2) {
      u16* dst = Cb + (long)segi * seg;
#pragma unroll
      for (int i = 0; i < 4; i++) {
        int r0 = rowBase + wr * 64 + i * 16 + lr;
#pragma unroll
        for (int j = 0; j < 4; j++) {
          int c0 = hb + wc * 64 + j * 16 + lc;
#pragma unroll
          for (int q = 0; q < 4; q++) dst[(long)(r0 + q) * D_DIM + c0] = f2bf(acc[i][j][q]);
        }
      }
    } else {
      u16* dst = Cb + 2 * seg;  // Vt [NBATCH][D_DIM][S_LEN]
#pragma unroll
      for (int i = 0; i < 4; i++) {
        int m0 = rowBase + wr * 64 + i * 16 + lr;
        int b = m0 >> 11, s0 = m0 & (S_LEN - 1);
#pragma unroll
        for (int j = 0; j < 4; j++) {
          int h = hb + wc * 64 + j * 16 + lc;
          u16x4 o;
          o[0] = f2bf(acc[i][j][0]); o[1] = f2bf(acc[i][j][1]);
          o[2] = f2bf(acc[i][j][2]); o[3] = f2bf(acc[i][j][3]);
          *reinterpret_cast<u16x4*>(dst + ((long)b * D_DIM + h) * S_LEN + s0) = o;
        }
      }
    }
  } else if (MODE == MODE_SC) {
    // P' = exp(s/32 - 8), causally masked; partial row sums -> aux[b][row][32]
    u16* Cb = (u16*)C + (long)bz * strideCb;
    float* lp = aux + (long)bz * S_LEN * 32;
#pragma unroll
    for (int i = 0; i < 4; i++) {
      int r0 = rowBase + wr * 64 + i * 16 + lr;
#pragma unroll
      for (int q = 0; q < 4; q++) {
        int r = r0 + q;
        float rs = 0.f;
#pragma unroll
        for (int j = 0; j < 4; j++) {
          int c0 = colBase + wc * 64 + j * 16 + lc;
          float p = (c0 <= r) ? __expf(acc[i][j][q] * 0.03125f - 8.f) : 0.f;
          rs += p;
          Cb[(long)r * ldc + c0] = f2bf(p);
        }
#pragma unroll
        for (int off = 1; off < 16; off <<= 1) rs += __shfl_xor(rs, off);
        if ((lane & 15) == 0) lp[r * 32 + bc * 2 + wc] = rs;
      }
    }
  } else {
    float* Cb = (float*)C + (long)bz * strideCb;
#pragma unroll
    for (int i = 0; i < 4; i++) {
      int r0 = rowBase + wr * 64 + i * 16 + lr;
#pragma unroll
      for (int j = 0; j < 4; j++) {
        int c0 = colBase + wc * 64 + j * 16 + lc;
#pragma unroll
        for (int q = 0; q < 4; q++)
          Cb[(long)(r0 + q) * ldc + c0] = acc[i][j][q] * ilds[wr * 64 + i * 16 + lr + q];
      }
    }
  }
}

extern "C" void kernel_launch(void* const* d_in, const int* in_sizes, int n_in,
                              void* d_out, int out_size, void* d_ws, size_t ws_size,
                              hipStream_t stream) {
  const float* x = (const float*)d_in[0];
  const float* Wq = (const float*)d_in[1];
  const float* Wk = (const float*)d_in[2];
  const float* Wv = (const float*)d_in[3];
  float* out = (float*)d_out;

  const size_t SD = (size_t)S_LEN * D_DIM;
  const size_t SS = (size_t)S_LEN * S_LEN;
  const size_t DD = (size_t)D_DIM * D_DIM;

  size_t off = 0;
  char* ws = (char*)d_ws;
  auto alloc = [&](size_t bytes) -> char* {
    char* p = ws + off;
    off += (bytes + 255) & ~(size_t)255;
    return p;
  };
  // xb and Wqkvb contiguous so cast_all writes one region
  u16* xb = (u16*)alloc((NBATCH * SD + 3 * DD) * 2);
  u16* Wqkvb = xb + NBATCH * SD;
  u16* QKVt = (u16*)alloc(3 * NBATCH * SD * 2);   // Qb | Kb | Vt
  u16* Qb = QKVt;
  u16* Kb = QKVt + NBATCH * SD;
  u16* Vt = QKVt + 2 * NBATCH * SD;
  size_t base_off = off;
  size_t need_full = base_off + ((NBATCH * SS * 2 + 255) & ~(size_t)255) +
                     ((NBATCH * (size_t)S_LEN * 32 * 4 + 255) & ~(size_t)255);
  const int nbpar = (ws_size >= need_full) ? NBATCH : 1;
  u16* P = (u16*)alloc((size_t)nbpar * SS * 2);
  float* l_part = (float*)alloc((size_t)nbpar * S_LEN * 32 * 4);

  cast_all<<<2048, 256, 0, stream>>>(x, Wq, Wk, Wv, xb);

  // fused QKV projection: M = 8192, N = 3072, K = 1024 (128^2, XCD-local panels)
  dim3 gp((NBATCH * S_LEN) / BM, 3 * D_DIM / BN, 1);
  gemm_bt<MODE_QKV><<<gp, 256, 0, stream>>>(xb, Wqkvb, QKVt, D_DIM, 0, 0, 0, D_DIM,
                                            nullptr, NBATCH);

  const int ntri = (S_LEN / BM) * (S_LEN / BM + 1) / 2;  // 136
  if (nbpar == NBATCH) {
    // SC: 1D grid 544 = 8 XCDs x 68 tiles; PV: 512 = 8 x 64 (batch-pair aligned)
    gemm_bt<MODE_SC><<<dim3(8 * 68, 1, 1), 256, 0, stream>>>(
        Qb, Kb, P, D_DIM, (long)SD, (long)SD, (long)SS, S_LEN, l_part, NBATCH);
    gemm_bt<MODE_PV><<<dim3(8 * 64, 1, 1), 256, 0, stream>>>(
        P, Vt, out, S_LEN, (long)SS, (long)SD, (long)SD, D_DIM, l_part, NBATCH);
  } else {
    for (int b = 0; b < NBATCH; ++b) {
      gemm_bt<MODE_SC><<<dim3(ntri, 1, 1), 256, 0, stream>>>(
          Qb + b * SD, Kb + b * SD, P, D_DIM, 0, 0, 0, S_LEN, l_part, 1);
      gemm_bt<MODE_PV><<<dim3(S_LEN / BM, D_DIM / BN, 1), 256, 0, stream>>>(
          P, Vt + b * SD, out + b * SD, S_LEN, 0, 0, 0, D_DIM, l_part, 1);
    }
  }
}

// Round 24
// 150.246 us; speedup vs baseline: 1.0563x; 1.0563x over previous
//
#include <hip/hip_runtime.h>
#include <hip/hip_bf16.h>
#include <stdint.h>

typedef unsigned short u16;
typedef __attribute__((ext_vector_type(8))) short short8;
typedef __attribute__((ext_vector_type(4))) float f32x4;
typedef __attribute__((ext_vector_type(4))) u16 u16x4;

#define S_LEN 2048
#define D_DIM 1024
#define NBATCH 4
#define BM 128
#define BN 128
#define BK 32

enum { MODE_QKV = 0, MODE_SC = 2, MODE_PV = 3 };

__device__ inline u16 f2bf(float f) {
  uint32_t u = __float_as_uint(f);
  uint32_t r = (u + 0x7fffu + ((u >> 16) & 1u)) >> 16;
  return (u16)r;
}

// one kernel casts x and the 3 weight matrices into the contiguous bf16 region
// out = [xb (NBATCH*S*D) | Wq (D*D) | Wk | Wv]
__global__ __launch_bounds__(256) void cast_all(
    const float* __restrict__ x, const float* __restrict__ wq,
    const float* __restrict__ wk, const float* __restrict__ wv,
    u16* __restrict__ out) {
  const int X4 = (NBATCH * S_LEN * D_DIM) / 4;
  const int W4 = (D_DIM * D_DIM) / 4;
  const int total = X4 + 3 * W4;
  int g = blockIdx.x * blockDim.x + threadIdx.x;
  int stride = gridDim.x * blockDim.x;
  for (; g < total; g += stride) {
    const float* src;
    int si;
    if (g < X4) { src = x; si = g; }
    else if (g < X4 + W4) { src = wq; si = g - X4; }
    else if (g < X4 + 2 * W4) { src = wk; si = g - X4 - W4; }
    else { src = wv; si = g - X4 - 2 * W4; }
    f32x4 v = *reinterpret_cast<const f32x4*>(src + (long)si * 4);
    u16x4 o;
    o[0] = f2bf(v[0]); o[1] = f2bf(v[1]); o[2] = f2bf(v[2]); o[3] = f2bf(v[3]);
    *reinterpret_cast<u16x4*>(out + (long)g * 4) = o;
  }
}

// C = A (bf16 [M,K]) * B^T (bf16 [N,K]) ; lda = ldb = K.
// Structure = R19 optimum (128^2/BK=32 2-phase; XCD-local QKV panels;
// batch-pair SC; CU-pair-balanced PV).
// NEW: T2-style slot swizzle. Bank = (row&1)<<4 | slot<<2 -> 8 lanes/bank on
// ds_read_b128. Involution: global SOURCE slot ^= (srow>>1)&3 (linear LDS dest,
// rule #21), read slot g ^= (l15>>1)&3 (same key per row). 8-way -> 2-way (free).
template <int MODE>
__global__ __launch_bounds__(256, 2) void gemm_bt(
    const u16* __restrict__ A, const u16* __restrict__ B, void* __restrict__ C,
    int K, long strideAb, long strideBb, long strideCb, int ldc,
    float* __restrict__ aux, int nb) {
  __shared__ u16 As[2][BM * BK];
  __shared__ u16 Bs[2][BN * BK];
  __shared__ float ilds[BM];

  int br, bc, bz;
  if (MODE == MODE_SC) {
    int t;
    if (nb == NBATCH) {
      int lin = blockIdx.x;          // 0..543
      int xcd = lin & 7;
      bz = xcd >> 1;                 // batch on XCD pair {2b,2b+1}
      t = (xcd & 1) * 68 + (lin >> 3);
    } else {
      bz = blockIdx.z;
      t = blockIdx.x;
    }
    int r = (int)((sqrtf(8.0f * (float)t + 1.0f) - 1.0f) * 0.5f);
    while ((r + 1) * (r + 2) / 2 <= t) ++r;
    while (r * (r + 1) / 2 > t) --r;
    br = r;
    bc = t - r * (r + 1) / 2;
  } else if (MODE == MODE_PV) {
    int xr, bcl, ch;
    if (nb == NBATCH) {
      int lin = blockIdx.x;          // 0..511
      int xcd = lin & 7;
      bz = xcd >> 1;
      ch = xcd & 1;                  // column half (Vt 2MB L2-resident)
      int rank = lin >> 3;           // 0..63
      xr = rank >> 2;                // 0..15
      bcl = rank & 3;
      // CU-pair-balanced: ranks c and c+32 co-reside; br(xr)+br(xr+8)=15.
      br = (xr < 8) ? (15 - 2 * xr) : (2 * (xr - 8));
      bc = ch * 4 + bcl;
    } else {
      bz = blockIdx.z;
      xr = blockIdx.x;
      int nt = S_LEN / BM;
      br = (xr & 1) ? (xr >> 1) : (nt - 1 - (xr >> 1));
      bc = blockIdx.y;
    }
  } else {
    // MODE_QKV: XCD-locality mapping (confirmed lin&7 -> XCD round-robin).
    int lin = blockIdx.y * gridDim.x + blockIdx.x;  // 0..1535
    int xcd = lin & 7;
    int rank = lin >> 3;        // 0..191
    br = xcd * 8 + (rank & 7);  // rows [1024*xcd, 1024*(xcd+1))
    bc = rank >> 3;             // 0..23
    bz = 0;
  }

  const u16* Ab = A + (long)bz * strideAb;
  const u16* Bb = B + (long)bz * strideBb;

  const int rowBase = br * BM;
  const int colBase = bc * BN;
  int nkt = (MODE == MODE_PV) ? (br + 1) * (BM / BK) : (K / BK);

  const int tid = threadIdx.x;
  const int lane = tid & 63;
  const int wave = tid >> 6;
  const int wr = wave >> 1, wc = wave & 1;
  const int l15 = lane & 15;
  const int g = lane >> 4;
  const int gsw = (g ^ ((l15 >> 1) & 3)) * 8;  // swizzled read slot (u16 units)

  if (MODE == MODE_PV) {
    // inline row_inv: 2 threads/row, parity-strided scalar sum (correct for any nslot)
    int row = tid >> 1, half = tid & 1;
    const float* lp = aux + (long)bz * S_LEN * 32 + (long)(rowBase + row) * 32;
    int nslot = 2 * (br + 1);  // slots SC wrote for this row-block
    float s = 0.f;
    for (int k = half; k < nslot; k += 2) s += lp[k];
    s += __shfl_xor(s, 1);
    if (half == 0) ilds[row] = 1.f / s;
  }

  f32x4 acc[4][4];
#pragma unroll
  for (int i = 0; i < 4; i++)
#pragma unroll
    for (int j = 0; j < 4; j++) acc[i][j] = f32x4{0.f, 0.f, 0.f, 0.f};

  const int srow = tid >> 2;                                  // 0..63
  const int skc = ((tid & 3) ^ ((srow >> 1) & 3)) * 8;        // pre-swizzled src slot

  auto stage = [&](int buf, int kt) {
    const u16* ga = Ab + (long)(rowBase + srow) * K + kt * BK + skc;
    const u16* gb = Bb + (long)(colBase + srow) * K + kt * BK + skc;
    __builtin_amdgcn_global_load_lds(
        (const __attribute__((address_space(1))) void*)ga,
        (__attribute__((address_space(3))) void*)(&As[buf][tid * 8]), 16, 0, 0);
    __builtin_amdgcn_global_load_lds(
        (const __attribute__((address_space(1))) void*)(ga + (long)64 * K),
        (__attribute__((address_space(3))) void*)(&As[buf][64 * BK + tid * 8]), 16, 0, 0);
    __builtin_amdgcn_global_load_lds(
        (const __attribute__((address_space(1))) void*)gb,
        (__attribute__((address_space(3))) void*)(&Bs[buf][tid * 8]), 16, 0, 0);
    __builtin_amdgcn_global_load_lds(
        (const __attribute__((address_space(1))) void*)(gb + (long)64 * K),
        (__attribute__((address_space(3))) void*)(&Bs[buf][64 * BK + tid * 8]), 16, 0, 0);
  };

  stage(0, 0);
  __syncthreads();  // drain tile-0 loads; also covers PV's ilds write
  int cur = 0;
  for (int kt = 0; kt < nkt; ++kt) {
    if (kt + 1 < nkt) stage(cur ^ 1, kt + 1);  // prefetch in flight during compute
    short8 af[4], bf[4];
#pragma unroll
    for (int i = 0; i < 4; i++)
      af[i] = *reinterpret_cast<const short8*>(
          &As[cur][(wr * 64 + i * 16 + l15) * BK + gsw]);
#pragma unroll
    for (int j = 0; j < 4; j++)
      bf[j] = *reinterpret_cast<const short8*>(
          &Bs[cur][(wc * 64 + j * 16 + l15) * BK + gsw]);
#pragma unroll
    for (int i = 0; i < 4; i++)
#pragma unroll
      for (int j = 0; j < 4; j++)
        acc[i][j] = __builtin_amdgcn_mfma_f32_16x16x32_bf16(af[i], bf[j], acc[i][j], 0, 0, 0);
    __syncthreads();  // vmcnt(0)+lgkmcnt(0)+barrier: next tile ready, buf reusable
    cur ^= 1;
  }

  const int lr = g * 4;
  const int lc = l15;

  if (MODE == MODE_QKV) {
    u16* Cb = (u16*)C;  // Qb base; Kb at +seg; Vt at +2*seg
    const long seg = (long)NBATCH * S_LEN * D_DIM;
    const int segi = colBase >> 10;
    const int hb = colBase & 1023;
    if (segi < 2) {
      u16* dst = Cb + (long)segi * seg;
#pragma unroll
      for (int i = 0; i < 4; i++) {
        int r0 = rowBase + wr * 64 + i * 16 + lr;
#pragma unroll
        for (int j = 0; j < 4; j++) {
          int c0 = hb + wc * 64 + j * 16 + lc;
#pragma unroll
          for (int q = 0; q < 4; q++) dst[(long)(r0 + q) * D_DIM + c0] = f2bf(acc[i][j][q]);
        }
      }
    } else {
      u16* dst = Cb + 2 * seg;  // Vt [NBATCH][D_DIM][S_LEN]
#pragma unroll
      for (int i = 0; i < 4; i++) {
        int m0 = rowBase + wr * 64 + i * 16 + lr;
        int b = m0 >> 11, s0 = m0 & (S_LEN - 1);
#pragma unroll
        for (int j = 0; j < 4; j++) {
          int h = hb + wc * 64 + j * 16 + lc;
          u16x4 o;
          o[0] = f2bf(acc[i][j][0]); o[1] = f2bf(acc[i][j][1]);
          o[2] = f2bf(acc[i][j][2]); o[3] = f2bf(acc[i][j][3]);
          *reinterpret_cast<u16x4*>(dst + ((long)b * D_DIM + h) * S_LEN + s0) = o;
        }
      }
    }
  } else if (MODE == MODE_SC) {
    // P' = exp(s/32 - 8), causally masked; partial row sums -> aux[b][row][32]
    u16* Cb = (u16*)C + (long)bz * strideCb;
    float* lp = aux + (long)bz * S_LEN * 32;
#pragma unroll
    for (int i = 0; i < 4; i++) {
      int r0 = rowBase + wr * 64 + i * 16 + lr;
#pragma unroll
      for (int q = 0; q < 4; q++) {
        int r = r0 + q;
        float rs = 0.f;
#pragma unroll
        for (int j = 0; j < 4; j++) {
          int c0 = colBase + wc * 64 + j * 16 + lc;
          float p = (c0 <= r) ? __expf(acc[i][j][q] * 0.03125f - 8.f) : 0.f;
          rs += p;
          Cb[(long)r * ldc + c0] = f2bf(p);
        }
#pragma unroll
        for (int off = 1; off < 16; off <<= 1) rs += __shfl_xor(rs, off);
        if ((lane & 15) == 0) lp[r * 32 + bc * 2 + wc] = rs;
      }
    }
  } else {
    float* Cb = (float*)C + (long)bz * strideCb;
#pragma unroll
    for (int i = 0; i < 4; i++) {
      int r0 = rowBase + wr * 64 + i * 16 + lr;
#pragma unroll
      for (int j = 0; j < 4; j++) {
        int c0 = colBase + wc * 64 + j * 16 + lc;
#pragma unroll
        for (int q = 0; q < 4; q++)
          Cb[(long)(r0 + q) * ldc + c0] = acc[i][j][q] * ilds[wr * 64 + i * 16 + lr + q];
      }
    }
  }
}

extern "C" void kernel_launch(void* const* d_in, const int* in_sizes, int n_in,
                              void* d_out, int out_size, void* d_ws, size_t ws_size,
                              hipStream_t stream) {
  const float* x = (const float*)d_in[0];
  const float* Wq = (const float*)d_in[1];
  const float* Wk = (const float*)d_in[2];
  const float* Wv = (const float*)d_in[3];
  float* out = (float*)d_out;

  const size_t SD = (size_t)S_LEN * D_DIM;
  const size_t SS = (size_t)S_LEN * S_LEN;
  const size_t DD = (size_t)D_DIM * D_DIM;

  size_t off = 0;
  char* ws = (char*)d_ws;
  auto alloc = [&](size_t bytes) -> char* {
    char* p = ws + off;
    off += (bytes + 255) & ~(size_t)255;
    return p;
  };
  // xb and Wqkvb contiguous so cast_all writes one region
  u16* xb = (u16*)alloc((NBATCH * SD + 3 * DD) * 2);
  u16* Wqkvb = xb + NBATCH * SD;
  u16* QKVt = (u16*)alloc(3 * NBATCH * SD * 2);   // Qb | Kb | Vt
  u16* Qb = QKVt;
  u16* Kb = QKVt + NBATCH * SD;
  u16* Vt = QKVt + 2 * NBATCH * SD;
  size_t base_off = off;
  size_t need_full = base_off + ((NBATCH * SS * 2 + 255) & ~(size_t)255) +
                     ((NBATCH * (size_t)S_LEN * 32 * 4 + 255) & ~(size_t)255);
  const int nbpar = (ws_size >= need_full) ? NBATCH : 1;
  u16* P = (u16*)alloc((size_t)nbpar * SS * 2);
  float* l_part = (float*)alloc((size_t)nbpar * S_LEN * 32 * 4);

  cast_all<<<2048, 256, 0, stream>>>(x, Wq, Wk, Wv, xb);

  // fused QKV projection: M = 8192, N = 3072, K = 1024 (128^2, XCD-local panels)
  dim3 gp((NBATCH * S_LEN) / BM, 3 * D_DIM / BN, 1);
  gemm_bt<MODE_QKV><<<gp, 256, 0, stream>>>(xb, Wqkvb, QKVt, D_DIM, 0, 0, 0, D_DIM,
                                            nullptr, NBATCH);

  const int ntri = (S_LEN / BM) * (S_LEN / BM + 1) / 2;  // 136
  if (nbpar == NBATCH) {
    // SC: 1D grid 544 = 8 XCDs x 68 tiles; PV: 512 = 8 x 64 (batch-pair aligned)
    gemm_bt<MODE_SC><<<dim3(8 * 68, 1, 1), 256, 0, stream>>>(
        Qb, Kb, P, D_DIM, (long)SD, (long)SD, (long)SS, S_LEN, l_part, NBATCH);
    gemm_bt<MODE_PV><<<dim3(8 * 64, 1, 1), 256, 0, stream>>>(
        P, Vt, out, S_LEN, (long)SS, (long)SD, (long)SD, D_DIM, l_part, NBATCH);
  } else {
    for (int b = 0; b < NBATCH; ++b) {
      gemm_bt<MODE_SC><<<dim3(ntri, 1, 1), 256, 0, stream>>>(
          Qb + b * SD, Kb + b * SD, P, D_DIM, 0, 0, 0, S_LEN, l_part, 1);
      gemm_bt<MODE_PV><<<dim3(S_LEN / BM, D_DIM / BN, 1), 256, 0, stream>>>(
          P, Vt + b * SD, out + b * SD, S_LEN, 0, 0, 0, D_DIM, l_part, 1);
    }
  }
}